// Round 10
// baseline (253.703 us; speedup 1.0000x reference)
//
#include <hip/hip_runtime.h>
#include <hip/hip_bf16.h>
#include <stdint.h>

typedef __bf16 bf16;
typedef __bf16 bf16x8 __attribute__((ext_vector_type(8)));
typedef __bf16 bf16x4 __attribute__((ext_vector_type(4)));
typedef float  f32x4  __attribute__((ext_vector_type(4)));
typedef float  f32x16 __attribute__((ext_vector_type(16)));

#define S_LEN  2048
#define NH     16
#define DKV    64
#define DMODEL 1024
#define LOG2E  1.4426950408889634f

// ---------------------------------------------------------------------------
// async global->LDS 16B copy. LDS dest is wave-uniform base + lane*16.
// ---------------------------------------------------------------------------
__device__ __forceinline__ void async_load16(const void* g, void* l) {
  __builtin_amdgcn_global_load_lds(
      (const __attribute__((address_space(1))) uint32_t*)(uintptr_t)g,
      (__attribute__((address_space(3))) uint32_t*)(uintptr_t)l,
      16, 0, 0);
}

// ---------------------------------------------------------------------------
// Transpose-cast W [K=1024][N=1024] fp32 -> Wt bf16 [N][K]. grid (32,32,4), block (32,8)
// ---------------------------------------------------------------------------
__global__ void transpose_w(const float* __restrict__ W0, const float* __restrict__ W1,
                            const float* __restrict__ W2, const float* __restrict__ W3,
                            bf16* __restrict__ T0, bf16* __restrict__ T1,
                            bf16* __restrict__ T2, bf16* __restrict__ T3)
{
  int z = blockIdx.z;
  const float* W = (z == 0) ? W0 : (z == 1) ? W1 : (z == 2) ? W2 : W3;
  bf16* T = (z == 0) ? T0 : (z == 1) ? T1 : (z == 2) ? T2 : T3;
  __shared__ float tile[32][33];
  int n0 = blockIdx.x * 32, k0 = blockIdx.y * 32;
  int tx = threadIdx.x, ty = threadIdx.y;
  for (int i = 0; i < 32; i += 8)
    tile[ty + i][tx] = W[(size_t)(k0 + ty + i) * DMODEL + n0 + tx];
  __syncthreads();
  for (int i = 0; i < 32; i += 8)
    T[(size_t)(n0 + ty + i) * DMODEL + k0 + tx] = (bf16)tile[tx][ty + i];
}

// ---------------------------------------------------------------------------
// QKV GEMM v2: fused fp32->bf16 cast on A; A in DOUBLE-BUFFERED LDS (one
// barrier per K-iter); B operand REGISTER-DIRECT from global (weights are
// L2-resident; per B-frag inst the wave's 4 quads cover one full 64B line
// per row -> no over-fetch). BK=32, 32 iters.
// grid (m=32, n=8, z=3): XCD = m%8 (A-tile L2-local).
// z<2: C bf16 head layout [B,NH,S,DKV] via LDS-restaged b128 stores.
// z==2: V in PV-permuted layout [bh][s/64][(s%64)/4][d][s%4].
// ---------------------------------------------------------------------------
__global__ __launch_bounds__(256) void gemm_qkv(
    const float* __restrict__ Aq, const float* __restrict__ Ak, const float* __restrict__ Av,
    const bf16* __restrict__ Bq, const bf16* __restrict__ Bk, const bf16* __restrict__ Bv,
    bf16* __restrict__ Cq, bf16* __restrict__ Ck, bf16* __restrict__ Cv)
{
  __shared__ __align__(16) char smem[16896];
  bf16* As = (bf16*)smem;                // dbuf [2][128*32] = 16KB
  bf16* Ls = (bf16*)smem;                // epilogue overlay [64][132] = 16.9KB

  const int z = blockIdx.z;
  const float* A = (z == 0) ? Aq : (z == 1) ? Ak : Av;
  const bf16* Bt = (z == 0) ? Bq : (z == 1) ? Bk : Bv;
  bf16* C        = (z == 0) ? Cq : (z == 1) ? Ck : Cv;

  const int m0 = blockIdx.x * 128;       // m on x: XCD-local A reuse
  const int n0 = blockIdx.y * 128;
  const int tid = threadIdx.x;
  const int lane = tid & 63;
  const int wave = tid >> 6;
  const int wm = (wave >> 1) * 64;
  const int wn = (wave & 1) * 64;
  const int row = lane & 15;
  const int quad = lane >> 4;

  f32x4 acc[4][4];
  for (int i = 0; i < 4; ++i)
    for (int j = 0; j < 4; ++j) acc[i][j] = (f32x4){0.f, 0.f, 0.f, 0.f};

  const int ar = tid >> 2;               // A row 0..63 (and +64)
  const int ac8 = (tid & 3) * 8;         // col group of 8
  const float* Ab0 = A + (size_t)(m0 + ar) * DMODEL + ac8;
  const float* Ab1 = Ab0 + (size_t)64 * DMODEL;
  const bf16*  Bb  = Bt + (size_t)(n0 + wn + row) * DMODEL + quad * 8;

  // preload A(0)
  f32x4 a00 = *(const f32x4*)(Ab0);
  f32x4 a01 = *(const f32x4*)(Ab0 + 4);
  f32x4 a10 = *(const f32x4*)(Ab1);
  f32x4 a11 = *(const f32x4*)(Ab1 + 4);

  for (int kt = 0; kt < 32; ++kt) {
    const int kk = kt << 5;
    bf16* Ab = As + (kt & 1) * 4096;
    bf16x8 o0, o1;
    for (int u = 0; u < 4; ++u) { o0[u] = (bf16)a00[u]; o0[u + 4] = (bf16)a01[u]; }
    for (int u = 0; u < 4; ++u) { o1[u] = (bf16)a10[u]; o1[u + 4] = (bf16)a11[u]; }
    *(bf16x8*)(Ab + ar * 32 + ac8) = o0;
    *(bf16x8*)(Ab + (ar + 64) * 32 + ac8) = o1;
    __syncthreads();                     // single barrier per iter (dbuf WAR-safe)
    if (kt < 31) {                       // prefetch A(kt+1): full MFMA phase in flight
      const int kn = kk + 32;
      a00 = *(const f32x4*)(Ab0 + kn);
      a01 = *(const f32x4*)(Ab0 + kn + 4);
      a10 = *(const f32x4*)(Ab1 + kn);
      a11 = *(const f32x4*)(Ab1 + kn + 4);
    }
    bf16x8 bfr[4];                       // B register-direct (L2-resident)
    for (int j = 0; j < 4; ++j)
      bfr[j] = *(const bf16x8*)(Bb + (size_t)j * 16 * DMODEL + kk);
    bf16x8 af[4];
    for (int i = 0; i < 4; ++i)
      af[i] = *(const bf16x8*)(Ab + (wm + i * 16 + row) * 32 + quad * 8);
    for (int i = 0; i < 4; ++i)
      for (int j = 0; j < 4; ++j)
        acc[i][j] = __builtin_amdgcn_mfma_f32_16x16x32_bf16(af[i], bfr[j], acc[i][j], 0, 0, 0);
  }

  if (z != 2) {
    // LDS-restaged coalesced epilogue -> [B,NH,S,DKV], 2 passes of 64 rows
    const int bq = m0 >> 11;
    for (int p = 0; p < 2; ++p) {
      __syncthreads();                    // all As readers done; Ls overlay safe
      if ((wave >> 1) == p) {
        for (int i = 0; i < 4; ++i)
          for (int j = 0; j < 4; ++j)
            for (int r = 0; r < 4; ++r)
              Ls[(i * 16 + quad * 4 + r) * 132 + wn + j * 16 + row] = (bf16)acc[i][j][r];
      }
      __syncthreads();
      for (int u = 0; u < 4; ++u) {
        int cc = u * 256 + tid;           // 1024 chunks of 16B
        int rloc = cc >> 4, c8 = (cc & 15) * 8;
        int s = (m0 + p * 64 + rloc) & 2047;
        int gn = n0 + c8;
        int h = gn >> 6, d = gn & 63;
        bf16x8 val = *(const bf16x8*)(Ls + rloc * 132 + c8);
        *(bf16x8*)(C + (((size_t)(bq * NH + h)) * S_LEN + s) * DKV + d) = val;
      }
    }
  } else {
    // V permuted for attn PV: [bh][tile=s/64][kb=(s%64)/4][d][sr=s%4]
    for (int i = 0; i < 4; ++i)
      for (int j = 0; j < 4; ++j) {
        int gm = m0 + wm + i * 16 + quad * 4;    // s base (r=0..3 consecutive)
        int gn = n0 + wn + j * 16 + row;
        int b = gm >> 11, s = gm & 2047;
        int h = gn >> 6,  d = gn & 63;
        int bh = b * NH + h;
        int tile = s >> 6, kb = (s & 63) >> 2;
        bf16x4 t;
        for (int r = 0; r < 4; ++r) t[r] = (bf16)acc[i][j][r];
        *(bf16x4*)(C + ((((size_t)bh * 32 + tile) * 16 + kb) * 64 + d) * 4) = t;
      }
  }
}

// ---------------------------------------------------------------------------
// Flash attention: S^T = K*Q^T via 32x32x16 MFMA; P stays in registers.
// KV-split via blockIdx.z; partial O BF16 + fp32 row-sums.
// grid (bh=32, q=16, zh=2): XCD = bh%8 -> each bh's K/V served from one L2.
// ---------------------------------------------------------------------------
__global__ __launch_bounds__(256, 4) void attn_kernel(
    const bf16* __restrict__ Qh, const bf16* __restrict__ Kh, const bf16* __restrict__ Vperm,
    const float* __restrict__ mask, bf16* __restrict__ Opart, float* __restrict__ Lpart)
{
  __shared__ __align__(16) bf16 Ks[64 * 64];    // [kv][d], chunk XOR-swizzled
  __shared__ __align__(16) bf16 Vts[64 * 64];   // [kb][d][4] linear (permuted)
  __shared__ __align__(16) float masks2[64];

  const int bh = blockIdx.x;                    // bh on x: XCD-local K/V reuse
  const int b = bh >> 4;
  const int q0 = blockIdx.y * 128;
  const int zh = blockIdx.z;                    // kv half
  const int tid = threadIdx.x;
  const int lane = tid & 63;
  const int wave = tid >> 6;
  const int ln = lane & 31;
  const int hi = lane >> 5;
  const float SC2 = 0.125f * LOG2E;

  // hoisted Q B-frags: B[k=d][n=q] = Q[q][d], d = c*16 + hi*8 + u
  const int qg = q0 + wave * 32 + ln;
  bf16x8 qf[4];
  {
    const bf16* qrow = Qh + ((size_t)bh * S_LEN + qg) * DKV;
    for (int c = 0; c < 4; ++c)
      qf[c] = *(const bf16x8*)(qrow + c * 16 + hi * 8);
  }

  f32x16 O[2];
  for (int nb = 0; nb < 2; ++nb)
    for (int i = 0; i < 16; ++i) O[nb][i] = 0.f;
  float lsum = 0.f;

  for (int it = 0; it < 16; ++it) {
    const int kv0 = zh * 1024 + it * 64;
    __syncthreads();  // protect Ks/Vts/masks2 from previous iteration's readers
    const bf16* vtile = Vperm + ((size_t)bh * 32 + (kv0 >> 6)) * 4096;
    for (int j = 0; j < 2; ++j) {
      int base = j * 256 + wave * 64;       // wave-uniform
      int idx = base + lane;
      int r = idx >> 3;
      int cc = (idx & 7) ^ (r & 7);
      async_load16(Kh + ((size_t)bh * S_LEN + kv0 + r) * DKV + cc * 8,
                   (char*)Ks + (size_t)base * 16);
      async_load16(vtile + (size_t)idx * 8,
                   (char*)Vts + (size_t)base * 16);
    }
    if (tid < 64) masks2[tid] = mask[b * S_LEN + kv0 + tid] * LOG2E;
    __syncthreads();

    // S^T = K * Q^T  (A = K[kv][d], m=kv: 2 m-blocks; B = qf; 4 k-chunks)
    f32x16 Sm[2];
    for (int i = 0; i < 16; ++i) { Sm[0][i] = 0.f; Sm[1][i] = 0.f; }
    for (int c = 0; c < 4; ++c) {
      bf16x8 k0 = *(const bf16x8*)(Ks + ln * 64        + (((2 * c + hi) ^ (ln & 7)) << 3));
      bf16x8 k1 = *(const bf16x8*)(Ks + (32 + ln) * 64 + (((2 * c + hi) ^ (ln & 7)) << 3));
      Sm[0] = __builtin_amdgcn_mfma_f32_32x32x16_bf16(k0, qf[c], Sm[0], 0, 0, 0);
      Sm[1] = __builtin_amdgcn_mfma_f32_32x32x16_bf16(k1, qf[c], Sm[1], 0, 0, 0);
    }

    // P = exp2(S*SC2 + mask*LOG2E) in registers -> PV
    for (int cg = 0; cg < 4; ++cg) {
      int mb = cg >> 1, g = cg & 1;
      int koff = 32 * mb + 16 * g + 4 * hi;
      f32x4 mklo = *(const f32x4*)(masks2 + koff);
      f32x4 mkhi = *(const f32x4*)(masks2 + koff + 8);
      bf16x8 ap;
      float ls0 = 0.f;
      for (int u = 0; u < 4; ++u) {
        float p = __builtin_amdgcn_exp2f(Sm[mb][g * 8 + u] * SC2 + mklo[u]);
        ls0 += p; ap[u] = (bf16)p;
      }
      for (int u = 0; u < 4; ++u) {
        float p = __builtin_amdgcn_exp2f(Sm[mb][g * 8 + 4 + u] * SC2 + mkhi[u]);
        ls0 += p; ap[4 + u] = (bf16)p;
      }
      lsum += ls0;
      int kb0 = hi + 4 * g + 8 * mb;
      for (int nb = 0; nb < 2; ++nb) {
        int d = nb * 32 + ln;
        bf16x4 lo = *(const bf16x4*)(Vts + ((size_t)kb0 * 64 + d) * 4);
        bf16x4 hv = *(const bf16x4*)(Vts + ((size_t)(kb0 + 2) * 64 + d) * 4);
        bf16x8 bv;
        for (int u = 0; u < 4; ++u) { bv[u] = lo[u]; bv[u + 4] = hv[u]; }
        O[nb] = __builtin_amdgcn_mfma_f32_32x32x16_bf16(ap, bv, O[nb], 0, 0, 0);
      }
    }
  }

  // partial row sums
  float lt = lsum + __shfl_xor(lsum, 32, 64);
  if (lane < 32)
    Lpart[((size_t)zh * 32 + bh) * S_LEN + q0 + wave * 32 + ln] = lt;

  // partial O (un-normalized, bf16): Opart[zh][bh][q][d]
  bf16* ob = Opart + (((size_t)zh * 32 + bh) * S_LEN) * DKV;
  for (int g = 0; g < 4; ++g)
    for (int nb = 0; nb < 2; ++nb)
      for (int j = 0; j < 4; ++j) {
        int qrow = q0 + wave * 32 + j + 8 * g + 4 * hi;
        ob[(size_t)qrow * DKV + nb * 32 + ln] = (bf16)O[nb][g * 4 + j];
      }
}

// ---------------------------------------------------------------------------
// Out-GEMM v2: fused combine+normalize on A (bf16 partials) into double-
// buffered LDS (one barrier/iter); B = Wot register-direct. BK=32.
// grid (m=64, n=8): XCD = m%8 -> Opart rows fetched once per XCD.
// ---------------------------------------------------------------------------
__global__ __launch_bounds__(256) void gemm_out(
    const bf16* __restrict__ Opart, const float* __restrict__ Lpart,
    const bf16* __restrict__ Wot, float* __restrict__ Cout)
{
  __shared__ __align__(16) bf16 As[2][64 * 32];  // 8KB dbuf
  __shared__ float rinv[NH * 64];                // 4KB

  const int m0 = blockIdx.x * 64;        // m on x: XCD-local Opart reuse
  const int n0 = blockIdx.y * 128;
  const int tid = threadIdx.x;
  const int lane = tid & 63;
  const int wave = tid >> 6;
  const int wm = (wave >> 1) * 32;
  const int wn = (wave & 1) * 64;
  const int row = lane & 15;
  const int quad = lane >> 4;
  const int b = m0 >> 11;
  const int s0 = m0 & 2047;

  // per-block row-sum reciprocals for all heads x 64 rows
  for (int u = 0; u < 4; ++u) {
    int idx = u * 256 + tid;
    int h = idx >> 6, r = idx & 63;
    float l = Lpart[((size_t)(b * NH + h)) * S_LEN + s0 + r]
            + Lpart[((size_t)(32 + b * NH + h)) * S_LEN + s0 + r];
    rinv[idx] = 1.0f / l;
  }
  __syncthreads();

  f32x4 acc[2][4];
  for (int i = 0; i < 2; ++i)
    for (int j = 0; j < 4; ++j) acc[i][j] = (f32x4){0.f, 0.f, 0.f, 0.f};

  const int ar = tid >> 2;               // A row 0..63
  const int ac8 = (tid & 3) * 8;
  const bf16* Bb = Wot + (size_t)(n0 + wn + row) * DMODEL + quad * 8;

  // preload A(0): head 0, d0 = ac8
  bf16x8 h0 = *(const bf16x8*)(Opart + ((size_t)(b * NH) * S_LEN + s0 + ar) * DKV + ac8);
  bf16x8 h1 = *(const bf16x8*)(Opart + ((size_t)(32 + b * NH) * S_LEN + s0 + ar) * DKV + ac8);

  for (int kt = 0; kt < 32; ++kt) {
    const int kk = kt << 5;
    const int h = kk >> 6;
    bf16* Ab = As[kt & 1];
    float rv = rinv[h * 64 + ar];
    bf16x8 o;
    for (int w = 0; w < 8; ++w)
      o[w] = (bf16)(((float)h0[w] + (float)h1[w]) * rv);
    *(bf16x8*)(Ab + ar * 32 + ac8) = o;
    __syncthreads();                     // single barrier per iter
    if (kt < 31) {                       // prefetch A(kt+1)
      const int kn = kk + 32;
      const int hn = kn >> 6;
      const int dn = (kn & 63) + ac8;
      h0 = *(const bf16x8*)(Opart + ((size_t)(b * NH + hn) * S_LEN + s0 + ar) * DKV + dn);
      h1 = *(const bf16x8*)(Opart + ((size_t)(32 + b * NH + hn) * S_LEN + s0 + ar) * DKV + dn);
    }
    bf16x8 bfr[4];                       // Wot register-direct
    for (int j = 0; j < 4; ++j)
      bfr[j] = *(const bf16x8*)(Bb + (size_t)j * 16 * DMODEL + kk);
    bf16x8 af[2];
    for (int i = 0; i < 2; ++i)
      af[i] = *(const bf16x8*)(Ab + (wm + i * 16 + row) * 32 + quad * 8);
    for (int i = 0; i < 2; ++i)
      for (int j = 0; j < 4; ++j)
        acc[i][j] = __builtin_amdgcn_mfma_f32_16x16x32_bf16(af[i], bfr[j], acc[i][j], 0, 0, 0);
  }

  for (int i = 0; i < 2; ++i)
    for (int j = 0; j < 4; ++j)
      for (int r = 0; r < 4; ++r) {
        int gm = m0 + wm + i * 16 + quad * 4 + r;
        int gn = n0 + wn + j * 16 + row;
        Cout[(size_t)gm * DMODEL + gn] = acc[i][j][r];
      }
}

// ---------------------------------------------------------------------------
extern "C" void kernel_launch(void* const* d_in, const int* in_sizes, int n_in,
                              void* d_out, int out_size, void* d_ws, size_t ws_size,
                              hipStream_t stream)
{
  const float* query = (const float*)d_in[0];
  const float* key_  = (const float*)d_in[1];
  const float* value = (const float*)d_in[2];
  const float* mask  = (const float*)d_in[3];
  const float* Wq = (const float*)d_in[4];
  const float* Wk = (const float*)d_in[5];
  const float* Wv = (const float*)d_in[6];
  const float* Wo = (const float*)d_in[7];

  char* ws = (char*)d_ws;
  const size_t MB = (size_t)1 << 20;
  bf16* qh    = (bf16*)(ws + 0 * MB);    // 8MB [B,NH,S,DKV]
  bf16* kh    = (bf16*)(ws + 8 * MB);    // 8MB [B,NH,S,DKV]
  bf16* vperm = (bf16*)(ws + 16 * MB);   // 8MB PV-permuted V
  bf16* wot   = (bf16*)(ws + 24 * MB);   // 2MB (live until out-GEMM)
  bf16* Opart = (bf16*)(ws + 26 * MB);   // 16MB bf16 partials (26..42)
  bf16* wqt   = (bf16*)(ws + 26 * MB);   // 2MB each, dead after QKV GEMM
  bf16* wkt   = (bf16*)(ws + 28 * MB);   //   (overlaid by Opart afterwards)
  bf16* wvt   = (bf16*)(ws + 30 * MB);
  float* Lpart = (float*)(ws + 58 * MB); // 512KB row-sum partials

  transpose_w<<<dim3(32, 32, 4), dim3(32, 8), 0, stream>>>(Wq, Wk, Wv, Wo, wqt, wkt, wvt, wot);
  gemm_qkv<<<dim3(32, 8, 3), 256, 0, stream>>>(query, key_, value, wqt, wkt, wvt,
                                               qh, kh, vperm);
  attn_kernel<<<dim3(32, 16, 2), 256, 0, stream>>>(qh, kh, vperm, mask, Opart, Lpart);
  gemm_out<<<dim3(64, 8), 256, 0, stream>>>(Opart, Lpart, wot, (float*)d_out);
}

// Round 11
// 217.222 us; speedup vs baseline: 1.1679x; 1.1679x over previous
//
#include <hip/hip_runtime.h>
#include <hip/hip_bf16.h>
#include <stdint.h>

typedef __bf16 bf16;
typedef __bf16 bf16x8 __attribute__((ext_vector_type(8)));
typedef __bf16 bf16x4 __attribute__((ext_vector_type(4)));
typedef float  f32x4  __attribute__((ext_vector_type(4)));
typedef float  f32x16 __attribute__((ext_vector_type(16)));

#define S_LEN  2048
#define NH     16
#define DKV    64
#define DMODEL 1024
#define LOG2E  1.4426950408889634f

// ---------------------------------------------------------------------------
// async global->LDS 16B copy. LDS dest is wave-uniform base + lane*16.
// ---------------------------------------------------------------------------
__device__ __forceinline__ void async_load16(const void* g, void* l) {
  __builtin_amdgcn_global_load_lds(
      (const __attribute__((address_space(1))) uint32_t*)(uintptr_t)g,
      (__attribute__((address_space(3))) uint32_t*)(uintptr_t)l,
      16, 0, 0);
}

// ---------------------------------------------------------------------------
// Transpose-cast W [K=1024][N=1024] fp32 -> Wt bf16 [N][K]. grid (32,32,4), block (32,8)
// ---------------------------------------------------------------------------
__global__ void transpose_w(const float* __restrict__ W0, const float* __restrict__ W1,
                            const float* __restrict__ W2, const float* __restrict__ W3,
                            bf16* __restrict__ T0, bf16* __restrict__ T1,
                            bf16* __restrict__ T2, bf16* __restrict__ T3)
{
  int z = blockIdx.z;
  const float* W = (z == 0) ? W0 : (z == 1) ? W1 : (z == 2) ? W2 : W3;
  bf16* T = (z == 0) ? T0 : (z == 1) ? T1 : (z == 2) ? T2 : T3;
  __shared__ float tile[32][33];
  int n0 = blockIdx.x * 32, k0 = blockIdx.y * 32;
  int tx = threadIdx.x, ty = threadIdx.y;
  for (int i = 0; i < 32; i += 8)
    tile[ty + i][tx] = W[(size_t)(k0 + ty + i) * DMODEL + n0 + tx];
  __syncthreads();
  for (int i = 0; i < 32; i += 8)
    T[(size_t)(n0 + ty + i) * DMODEL + k0 + tx] = (bf16)tile[tx][ty + i];
}

// ---------------------------------------------------------------------------
// QKV GEMM: fused fp32->bf16 cast on A; 64x128 tile, BK=64 (round-9 K-loop:
// async-DMA B with source-folded XOR swizzle, 128B LDS rows, 2 barriers).
// grid (m=64, n=8, z=3) = 1536 blocks -> 6 blocks/CU; XCD = m%8 (A L2-local).
// z<2: C bf16 head layout [B,NH,S,DKV] via LDS-restaged b128 stores.
// z==2: V in PV-permuted layout [bh][s/64][(s%64)/4][d][s%4].
// ---------------------------------------------------------------------------
__global__ __launch_bounds__(256) void gemm_qkv(
    const float* __restrict__ Aq, const float* __restrict__ Ak, const float* __restrict__ Av,
    const bf16* __restrict__ Bq, const bf16* __restrict__ Bk, const bf16* __restrict__ Bv,
    bf16* __restrict__ Cq, bf16* __restrict__ Ck, bf16* __restrict__ Cv)
{
  __shared__ __align__(16) char smem[24576];   // As 8K [64][64] + Bs 16K [128][64]
  bf16* As = (bf16*)smem;
  bf16* Bs = (bf16*)smem + 64 * 64;
  bf16* Ls = (bf16*)smem;                // epilogue overlay [64][132] = 16.9KB

  const int z = blockIdx.z;
  const float* A = (z == 0) ? Aq : (z == 1) ? Ak : Av;
  const bf16* Bt = (z == 0) ? Bq : (z == 1) ? Bk : Bv;
  bf16* C        = (z == 0) ? Cq : (z == 1) ? Ck : Cv;

  const int m0 = blockIdx.x * 64;        // m on x: XCD-local A reuse
  const int n0 = blockIdx.y * 128;
  const int tid = threadIdx.x;
  const int lane = tid & 63;
  const int wave = tid >> 6;
  const int wm = (wave >> 1) * 32;
  const int wn = (wave & 1) * 64;
  const int row = lane & 15;
  const int quad = lane >> 4;

  f32x4 acc[2][4];
  for (int i = 0; i < 2; ++i)
    for (int j = 0; j < 4; ++j) acc[i][j] = (f32x4){0.f, 0.f, 0.f, 0.f};

  // A staging: chunk id = u*256+tid: r = id>>3 (8-lane phases share a row ->
  // conflict-free), c = id&7; 32B fp32 -> 16B bf16 chunk, XOR-swizzled store.
  const int arc = tid & 7;
  const int arr = tid >> 3;              // 0..31; u adds 32

  for (int kt = 0; kt < 16; ++kt) {
    const int kk = kt << 6;
    f32x4 av0[2], av1[2];
    for (int u = 0; u < 2; ++u) {
      const float* sp = A + (size_t)(m0 + u * 32 + arr) * DMODEL + kk + arc * 8;
      av0[u] = *(const f32x4*)sp;
      av1[u] = *(const f32x4*)(sp + 4);
    }
    __syncthreads();
    for (int j = 0; j < 4; ++j) {        // B tile: async 1024 chunks, swizzle in src
      int base = j * 256 + wave * 64;
      int idx = base + lane;
      int r = idx >> 3;
      int cc = (idx & 7) ^ (r & 7);
      async_load16(Bt + (size_t)(n0 + r) * DMODEL + kk + cc * 8,
                   (char*)Bs + (size_t)base * 16);
    }
    for (int u = 0; u < 2; ++u) {
      bf16x8 o;
      for (int w = 0; w < 4; ++w) { o[w] = (bf16)av0[u][w]; o[w + 4] = (bf16)av1[u][w]; }
      int r = u * 32 + arr;
      *(bf16x8*)(As + r * 64 + ((arc ^ (r & 7)) << 3)) = o;
    }
    __syncthreads();
    for (int ks = 0; ks < 2; ++ks) {
      bf16x8 af[2], bfr[4];
      for (int i = 0; i < 2; ++i) {
        int rr = wm + i * 16 + row;
        af[i] = *(const bf16x8*)(As + rr * 64 + (((quad + ks * 4) ^ (rr & 7)) << 3));
      }
      for (int j = 0; j < 4; ++j) {
        int rr = wn + j * 16 + row;
        bfr[j] = *(const bf16x8*)(Bs + rr * 64 + (((quad + ks * 4) ^ (rr & 7)) << 3));
      }
      for (int i = 0; i < 2; ++i)
        for (int j = 0; j < 4; ++j)
          acc[i][j] = __builtin_amdgcn_mfma_f32_16x16x32_bf16(af[i], bfr[j], acc[i][j], 0, 0, 0);
    }
  }

  if (z != 2) {
    // LDS-restaged coalesced epilogue -> [B,NH,S,DKV], single pass (64 rows)
    const int bq = m0 >> 11;
    __syncthreads();                      // all As/Bs readers done; Ls overlay safe
    for (int i = 0; i < 2; ++i)
      for (int j = 0; j < 4; ++j)
        for (int r = 0; r < 4; ++r)
          Ls[(wm + i * 16 + quad * 4 + r) * 132 + wn + j * 16 + row] = (bf16)acc[i][j][r];
    __syncthreads();
    for (int u = 0; u < 4; ++u) {
      int cc = u * 256 + tid;             // 1024 chunks of 16B
      int rloc = cc >> 4, c8 = (cc & 15) * 8;
      int s = (m0 + rloc) & 2047;
      int gn = n0 + c8;
      int h = gn >> 6, d = gn & 63;
      bf16x8 val = *(const bf16x8*)(Ls + rloc * 132 + c8);
      *(bf16x8*)(C + (((size_t)(bq * NH + h)) * S_LEN + s) * DKV + d) = val;
    }
  } else {
    // V permuted for attn PV: [bh][tile=s/64][kb=(s%64)/4][d][sr=s%4]
    for (int i = 0; i < 2; ++i)
      for (int j = 0; j < 4; ++j) {
        int gm = m0 + wm + i * 16 + quad * 4;    // s base (r=0..3 consecutive)
        int gn = n0 + wn + j * 16 + row;
        int b = gm >> 11, s = gm & 2047;
        int h = gn >> 6,  d = gn & 63;
        int bh = b * NH + h;
        int tile = s >> 6, kb = (s & 63) >> 2;
        bf16x4 t;
        for (int r = 0; r < 4; ++r) t[r] = (bf16)acc[i][j][r];
        *(bf16x4*)(C + ((((size_t)bh * 32 + tile) * 16 + kb) * 64 + d) * 4) = t;
      }
  }
}

// ---------------------------------------------------------------------------
// Flash attention: S^T = K*Q^T via 32x32x16 MFMA; P stays in registers.
// KV-split via blockIdx.z; partial O BF16 + fp32 row-sums.
// grid (bh=32, q=16, zh=2): XCD = bh%8 -> each bh's K/V served from one L2.
// ---------------------------------------------------------------------------
__global__ __launch_bounds__(256, 4) void attn_kernel(
    const bf16* __restrict__ Qh, const bf16* __restrict__ Kh, const bf16* __restrict__ Vperm,
    const float* __restrict__ mask, bf16* __restrict__ Opart, float* __restrict__ Lpart)
{
  __shared__ __align__(16) bf16 Ks[64 * 64];    // [kv][d], chunk XOR-swizzled
  __shared__ __align__(16) bf16 Vts[64 * 64];   // [kb][d][4] linear (permuted)
  __shared__ __align__(16) float masks2[64];

  const int bh = blockIdx.x;                    // bh on x: XCD-local K/V reuse
  const int b = bh >> 4;
  const int q0 = blockIdx.y * 128;
  const int zh = blockIdx.z;                    // kv half
  const int tid = threadIdx.x;
  const int lane = tid & 63;
  const int wave = tid >> 6;
  const int ln = lane & 31;
  const int hi = lane >> 5;
  const float SC2 = 0.125f * LOG2E;

  // hoisted Q B-frags: B[k=d][n=q] = Q[q][d], d = c*16 + hi*8 + u
  const int qg = q0 + wave * 32 + ln;
  bf16x8 qf[4];
  {
    const bf16* qrow = Qh + ((size_t)bh * S_LEN + qg) * DKV;
    for (int c = 0; c < 4; ++c)
      qf[c] = *(const bf16x8*)(qrow + c * 16 + hi * 8);
  }

  f32x16 O[2];
  for (int nb = 0; nb < 2; ++nb)
    for (int i = 0; i < 16; ++i) O[nb][i] = 0.f;
  float lsum = 0.f;

  for (int it = 0; it < 16; ++it) {
    const int kv0 = zh * 1024 + it * 64;
    __syncthreads();  // protect Ks/Vts/masks2 from previous iteration's readers
    const bf16* vtile = Vperm + ((size_t)bh * 32 + (kv0 >> 6)) * 4096;
    for (int j = 0; j < 2; ++j) {
      int base = j * 256 + wave * 64;       // wave-uniform
      int idx = base + lane;
      int r = idx >> 3;
      int cc = (idx & 7) ^ (r & 7);
      async_load16(Kh + ((size_t)bh * S_LEN + kv0 + r) * DKV + cc * 8,
                   (char*)Ks + (size_t)base * 16);
      async_load16(vtile + (size_t)idx * 8,
                   (char*)Vts + (size_t)base * 16);
    }
    if (tid < 64) masks2[tid] = mask[b * S_LEN + kv0 + tid] * LOG2E;
    __syncthreads();

    // S^T = K * Q^T  (A = K[kv][d], m=kv: 2 m-blocks; B = qf; 4 k-chunks)
    f32x16 Sm[2];
    for (int i = 0; i < 16; ++i) { Sm[0][i] = 0.f; Sm[1][i] = 0.f; }
    for (int c = 0; c < 4; ++c) {
      bf16x8 k0 = *(const bf16x8*)(Ks + ln * 64        + (((2 * c + hi) ^ (ln & 7)) << 3));
      bf16x8 k1 = *(const bf16x8*)(Ks + (32 + ln) * 64 + (((2 * c + hi) ^ (ln & 7)) << 3));
      Sm[0] = __builtin_amdgcn_mfma_f32_32x32x16_bf16(k0, qf[c], Sm[0], 0, 0, 0);
      Sm[1] = __builtin_amdgcn_mfma_f32_32x32x16_bf16(k1, qf[c], Sm[1], 0, 0, 0);
    }

    // P = exp2(S*SC2 + mask*LOG2E) in registers -> PV
    for (int cg = 0; cg < 4; ++cg) {
      int mb = cg >> 1, g = cg & 1;
      int koff = 32 * mb + 16 * g + 4 * hi;
      f32x4 mklo = *(const f32x4*)(masks2 + koff);
      f32x4 mkhi = *(const f32x4*)(masks2 + koff + 8);
      bf16x8 ap;
      float ls0 = 0.f;
      for (int u = 0; u < 4; ++u) {
        float p = __builtin_amdgcn_exp2f(Sm[mb][g * 8 + u] * SC2 + mklo[u]);
        ls0 += p; ap[u] = (bf16)p;
      }
      for (int u = 0; u < 4; ++u) {
        float p = __builtin_amdgcn_exp2f(Sm[mb][g * 8 + 4 + u] * SC2 + mkhi[u]);
        ls0 += p; ap[4 + u] = (bf16)p;
      }
      lsum += ls0;
      int kb0 = hi + 4 * g + 8 * mb;
      for (int nb = 0; nb < 2; ++nb) {
        int d = nb * 32 + ln;
        bf16x4 lo = *(const bf16x4*)(Vts + ((size_t)kb0 * 64 + d) * 4);
        bf16x4 hv = *(const bf16x4*)(Vts + ((size_t)(kb0 + 2) * 64 + d) * 4);
        bf16x8 bv;
        for (int u = 0; u < 4; ++u) { bv[u] = lo[u]; bv[u + 4] = hv[u]; }
        O[nb] = __builtin_amdgcn_mfma_f32_32x32x16_bf16(ap, bv, O[nb], 0, 0, 0);
      }
    }
  }

  // partial row sums
  float lt = lsum + __shfl_xor(lsum, 32, 64);
  if (lane < 32)
    Lpart[((size_t)zh * 32 + bh) * S_LEN + q0 + wave * 32 + ln] = lt;

  // partial O (un-normalized, bf16): Opart[zh][bh][q][d]
  bf16* ob = Opart + (((size_t)zh * 32 + bh) * S_LEN) * DKV;
  for (int g = 0; g < 4; ++g)
    for (int nb = 0; nb < 2; ++nb)
      for (int j = 0; j < 4; ++j) {
        int qrow = q0 + wave * 32 + j + 8 * g + 4 * hi;
        ob[(size_t)qrow * DKV + nb * 32 + ln] = (bf16)O[nb][g * 4 + j];
      }
}

// ---------------------------------------------------------------------------
// Out-GEMM: fused combine+normalize on A (bf16 partials); 32x128 tile, BK=64
// (round-9 K-loop). grid (m=128, n=8) = 1024 blocks -> 4 blocks/CU; XCD = m%8.
// ---------------------------------------------------------------------------
__global__ __launch_bounds__(256) void gemm_out(
    const bf16* __restrict__ Opart, const float* __restrict__ Lpart,
    const bf16* __restrict__ Wot, float* __restrict__ Cout)
{
  __shared__ __align__(16) bf16 As[32 * 64];     // 4KB  swizzled
  __shared__ __align__(16) bf16 Bs[128 * 64];    // 16KB swizzled
  __shared__ float rinv[NH * 32];                // 2KB

  const int m0 = blockIdx.x * 32;        // m on x: XCD-local Opart reuse
  const int n0 = blockIdx.y * 128;
  const int tid = threadIdx.x;
  const int lane = tid & 63;
  const int wave = tid >> 6;
  const int wm = (wave >> 1) * 16;
  const int wn = (wave & 1) * 64;
  const int row = lane & 15;
  const int quad = lane >> 4;
  const int b = m0 >> 11;
  const int s0 = m0 & 2047;

  // per-block row-sum reciprocals for all heads x 32 rows
  for (int u = 0; u < 2; ++u) {
    int idx = u * 256 + tid;
    int h = idx >> 5, r = idx & 31;
    float l = Lpart[((size_t)(b * NH + h)) * S_LEN + s0 + r]
            + Lpart[((size_t)(32 + b * NH + h)) * S_LEN + s0 + r];
    rinv[idx] = 1.0f / l;
  }

  f32x4 acc[4];
  for (int j = 0; j < 4; ++j) acc[j] = (f32x4){0.f, 0.f, 0.f, 0.f};

  const int arc = tid & 7;               // chunk col
  const int arr = tid >> 3;              // row 0..31

  for (int kt = 0; kt < 16; ++kt) {      // kt == head index (BK=64 == DKV)
    bf16x8 h0 = *(const bf16x8*)(Opart + ((size_t)(b * NH + kt) * S_LEN + s0 + arr) * DKV + arc * 8);
    bf16x8 h1 = *(const bf16x8*)(Opart + ((size_t)(32 + b * NH + kt) * S_LEN + s0 + arr) * DKV + arc * 8);
    __syncthreads();
    for (int j = 0; j < 4; ++j) {        // Wot tile: async 1024 chunks, swizzled src
      int base = j * 256 + wave * 64;
      int idx = base + lane;
      int r = idx >> 3;
      int cc = (idx & 7) ^ (r & 7);
      async_load16(Wot + (size_t)(n0 + r) * DMODEL + kt * 64 + cc * 8,
                   (char*)Bs + (size_t)base * 16);
    }
    {
      float rv = rinv[kt * 32 + arr];
      bf16x8 o;
      for (int w = 0; w < 8; ++w)
        o[w] = (bf16)(((float)h0[w] + (float)h1[w]) * rv);
      *(bf16x8*)(As + arr * 64 + ((arc ^ (arr & 7)) << 3)) = o;
    }
    __syncthreads();
    for (int ks = 0; ks < 2; ++ks) {
      bf16x8 af, bfr[4];
      {
        int rr = wm + row;
        af = *(const bf16x8*)(As + rr * 64 + (((quad + ks * 4) ^ (rr & 7)) << 3));
      }
      for (int j = 0; j < 4; ++j) {
        int rr = wn + j * 16 + row;
        bfr[j] = *(const bf16x8*)(Bs + rr * 64 + (((quad + ks * 4) ^ (rr & 7)) << 3));
      }
      for (int j = 0; j < 4; ++j)
        acc[j] = __builtin_amdgcn_mfma_f32_16x16x32_bf16(af, bfr[j], acc[j], 0, 0, 0);
    }
  }

  for (int j = 0; j < 4; ++j)
    for (int r = 0; r < 4; ++r) {
      int gm = m0 + wm + quad * 4 + r;
      int gn = n0 + wn + j * 16 + row;
      Cout[(size_t)gm * DMODEL + gn] = acc[j][r];
    }
}

// ---------------------------------------------------------------------------
extern "C" void kernel_launch(void* const* d_in, const int* in_sizes, int n_in,
                              void* d_out, int out_size, void* d_ws, size_t ws_size,
                              hipStream_t stream)
{
  const float* query = (const float*)d_in[0];
  const float* key_  = (const float*)d_in[1];
  const float* value = (const float*)d_in[2];
  const float* mask  = (const float*)d_in[3];
  const float* Wq = (const float*)d_in[4];
  const float* Wk = (const float*)d_in[5];
  const float* Wv = (const float*)d_in[6];
  const float* Wo = (const float*)d_in[7];

  char* ws = (char*)d_ws;
  const size_t MB = (size_t)1 << 20;
  bf16* qh    = (bf16*)(ws + 0 * MB);    // 8MB [B,NH,S,DKV]
  bf16* kh    = (bf16*)(ws + 8 * MB);    // 8MB [B,NH,S,DKV]
  bf16* vperm = (bf16*)(ws + 16 * MB);   // 8MB PV-permuted V
  bf16* wot   = (bf16*)(ws + 24 * MB);   // 2MB (live until out-GEMM)
  bf16* Opart = (bf16*)(ws + 26 * MB);   // 16MB bf16 partials (26..42)
  bf16* wqt   = (bf16*)(ws + 26 * MB);   // 2MB each, dead after QKV GEMM
  bf16* wkt   = (bf16*)(ws + 28 * MB);   //   (overlaid by Opart afterwards)
  bf16* wvt   = (bf16*)(ws + 30 * MB);
  float* Lpart = (float*)(ws + 58 * MB); // 512KB row-sum partials

  transpose_w<<<dim3(32, 32, 4), dim3(32, 8), 0, stream>>>(Wq, Wk, Wv, Wo, wqt, wkt, wvt, wot);
  gemm_qkv<<<dim3(64, 8, 3), 256, 0, stream>>>(query, key_, value, wqt, wkt, wvt,
                                               qh, kh, vperm);
  attn_kernel<<<dim3(32, 16, 2), 256, 0, stream>>>(qh, kh, vperm, mask, Opart, Lpart);
  gemm_out<<<dim3(128, 8), 256, 0, stream>>>(Opart, Lpart, wot, (float*)d_out);
}

// Round 12
// 215.086 us; speedup vs baseline: 1.1795x; 1.0099x over previous
//
#include <hip/hip_runtime.h>
#include <hip/hip_bf16.h>
#include <stdint.h>

typedef __bf16 bf16;
typedef __bf16 bf16x8 __attribute__((ext_vector_type(8)));
typedef __bf16 bf16x4 __attribute__((ext_vector_type(4)));
typedef float  f32x4  __attribute__((ext_vector_type(4)));
typedef float  f32x16 __attribute__((ext_vector_type(16)));

#define S_LEN  2048
#define NH     16
#define DKV    64
#define DMODEL 1024
#define LOG2E  1.4426950408889634f

// ---------------------------------------------------------------------------
// async global->LDS 16B copy. LDS dest is wave-uniform base + lane*16.
// ---------------------------------------------------------------------------
__device__ __forceinline__ void async_load16(const void* g, void* l) {
  __builtin_amdgcn_global_load_lds(
      (const __attribute__((address_space(1))) uint32_t*)(uintptr_t)g,
      (__attribute__((address_space(3))) uint32_t*)(uintptr_t)l,
      16, 0, 0);
}

// ---------------------------------------------------------------------------
// Transpose-cast W [K=1024][N=1024] fp32 -> Wt bf16 [N][K]. grid (32,32,4), block (32,8)
// ---------------------------------------------------------------------------
__global__ void transpose_w(const float* __restrict__ W0, const float* __restrict__ W1,
                            const float* __restrict__ W2, const float* __restrict__ W3,
                            bf16* __restrict__ T0, bf16* __restrict__ T1,
                            bf16* __restrict__ T2, bf16* __restrict__ T3)
{
  int z = blockIdx.z;
  const float* W = (z == 0) ? W0 : (z == 1) ? W1 : (z == 2) ? W2 : W3;
  bf16* T = (z == 0) ? T0 : (z == 1) ? T1 : (z == 2) ? T2 : T3;
  __shared__ float tile[32][33];
  int n0 = blockIdx.x * 32, k0 = blockIdx.y * 32;
  int tx = threadIdx.x, ty = threadIdx.y;
  for (int i = 0; i < 32; i += 8)
    tile[ty + i][tx] = W[(size_t)(k0 + ty + i) * DMODEL + n0 + tx];
  __syncthreads();
  for (int i = 0; i < 32; i += 8)
    T[(size_t)(n0 + ty + i) * DMODEL + k0 + tx] = (bf16)tile[tx][ty + i];
}

// ---------------------------------------------------------------------------
// QKV GEMM: fused fp32->bf16 cast on A; 64x128 tile, BK=64; round-11 K-loop
// + A(k+1) REGISTER PREFETCH issued after barrier2 (overlaps MFMA phase).
// Queue-safe: A loads are OLDER than the next iter's B DMAs, so the cvt's
// vmcnt wait (=16) leaves all B DMAs in flight.
// grid (m=64, n=8, z=3) = 1536 blocks -> 6 blocks/CU; XCD = m%8 (A L2-local).
// z<2: C bf16 head layout [B,NH,S,DKV] via LDS-restaged b128 stores.
// z==2: V in PV-permuted layout [bh][s/64][(s%64)/4][d][s%4].
// ---------------------------------------------------------------------------
__global__ __launch_bounds__(256) void gemm_qkv(
    const float* __restrict__ Aq, const float* __restrict__ Ak, const float* __restrict__ Av,
    const bf16* __restrict__ Bq, const bf16* __restrict__ Bk, const bf16* __restrict__ Bv,
    bf16* __restrict__ Cq, bf16* __restrict__ Ck, bf16* __restrict__ Cv)
{
  __shared__ __align__(16) char smem[24576];   // As 8K [64][64] + Bs 16K [128][64]
  bf16* As = (bf16*)smem;
  bf16* Bs = (bf16*)smem + 64 * 64;
  bf16* Ls = (bf16*)smem;                // epilogue overlay [64][132] = 16.9KB

  const int z = blockIdx.z;
  const float* A = (z == 0) ? Aq : (z == 1) ? Ak : Av;
  const bf16* Bt = (z == 0) ? Bq : (z == 1) ? Bk : Bv;
  bf16* C        = (z == 0) ? Cq : (z == 1) ? Ck : Cv;

  const int m0 = blockIdx.x * 64;        // m on x: XCD-local A reuse
  const int n0 = blockIdx.y * 128;
  const int tid = threadIdx.x;
  const int lane = tid & 63;
  const int wave = tid >> 6;
  const int wm = (wave >> 1) * 32;
  const int wn = (wave & 1) * 64;
  const int row = lane & 15;
  const int quad = lane >> 4;

  f32x4 acc[2][4];
  for (int i = 0; i < 2; ++i)
    for (int j = 0; j < 4; ++j) acc[i][j] = (f32x4){0.f, 0.f, 0.f, 0.f};

  // A staging: chunk id: r = tid>>3 (8-lane phases share a row -> conflict-
  // free), c = tid&7; 32B fp32 -> 16B bf16 chunk, XOR-swizzled store.
  const int arc = tid & 7;
  const int arr = tid >> 3;              // 0..31; u adds 32
  const float* A0p = A + (size_t)(m0 + arr) * DMODEL + arc * 8;
  const float* A1p = A + (size_t)(m0 + 32 + arr) * DMODEL + arc * 8;

  // preload A(0)
  f32x4 av0[2], av1[2];
  av0[0] = *(const f32x4*)(A0p);
  av1[0] = *(const f32x4*)(A0p + 4);
  av0[1] = *(const f32x4*)(A1p);
  av1[1] = *(const f32x4*)(A1p + 4);

  for (int kt = 0; kt < 16; ++kt) {
    const int kk = kt << 6;
    __syncthreads();                     // barrier1: prev iter's readers done
    for (int j = 0; j < 4; ++j) {        // B tile: async 1024 chunks, swizzle in src
      int base = j * 256 + wave * 64;
      int idx = base + lane;
      int r = idx >> 3;
      int cc = (idx & 7) ^ (r & 7);
      async_load16(Bt + (size_t)(n0 + r) * DMODEL + kk + cc * 8,
                   (char*)Bs + (size_t)base * 16);
    }
    for (int u = 0; u < 2; ++u) {        // cvt + write A from prefetched regs
      bf16x8 o;
      for (int w = 0; w < 4; ++w) { o[w] = (bf16)av0[u][w]; o[w + 4] = (bf16)av1[u][w]; }
      int r = u * 32 + arr;
      *(bf16x8*)(As + r * 64 + ((arc ^ (r & 7)) << 3)) = o;
    }
    __syncthreads();                     // barrier2: staging visible
    if (kt < 15) {                       // prefetch A(kt+1) during MFMA phase
      const int kn = kk + 64;
      av0[0] = *(const f32x4*)(A0p + kn);
      av1[0] = *(const f32x4*)(A0p + kn + 4);
      av0[1] = *(const f32x4*)(A1p + kn);
      av1[1] = *(const f32x4*)(A1p + kn + 4);
    }
    for (int ks = 0; ks < 2; ++ks) {
      bf16x8 af[2], bfr[4];
      for (int i = 0; i < 2; ++i) {
        int rr = wm + i * 16 + row;
        af[i] = *(const bf16x8*)(As + rr * 64 + (((quad + ks * 4) ^ (rr & 7)) << 3));
      }
      for (int j = 0; j < 4; ++j) {
        int rr = wn + j * 16 + row;
        bfr[j] = *(const bf16x8*)(Bs + rr * 64 + (((quad + ks * 4) ^ (rr & 7)) << 3));
      }
      for (int i = 0; i < 2; ++i)
        for (int j = 0; j < 4; ++j)
          acc[i][j] = __builtin_amdgcn_mfma_f32_16x16x32_bf16(af[i], bfr[j], acc[i][j], 0, 0, 0);
    }
  }

  if (z != 2) {
    // LDS-restaged coalesced epilogue -> [B,NH,S,DKV], single pass (64 rows)
    const int bq = m0 >> 11;
    __syncthreads();                      // all As/Bs readers done; Ls overlay safe
    for (int i = 0; i < 2; ++i)
      for (int j = 0; j < 4; ++j)
        for (int r = 0; r < 4; ++r)
          Ls[(wm + i * 16 + quad * 4 + r) * 132 + wn + j * 16 + row] = (bf16)acc[i][j][r];
    __syncthreads();
    for (int u = 0; u < 4; ++u) {
      int cc = u * 256 + tid;             // 1024 chunks of 16B
      int rloc = cc >> 4, c8 = (cc & 15) * 8;
      int s = (m0 + rloc) & 2047;
      int gn = n0 + c8;
      int h = gn >> 6, d = gn & 63;
      bf16x8 val = *(const bf16x8*)(Ls + rloc * 132 + c8);
      *(bf16x8*)(C + (((size_t)(bq * NH + h)) * S_LEN + s) * DKV + d) = val;
    }
  } else {
    // V permuted for attn PV: [bh][tile=s/64][kb=(s%64)/4][d][sr=s%4]
    for (int i = 0; i < 2; ++i)
      for (int j = 0; j < 4; ++j) {
        int gm = m0 + wm + i * 16 + quad * 4;    // s base (r=0..3 consecutive)
        int gn = n0 + wn + j * 16 + row;
        int b = gm >> 11, s = gm & 2047;
        int h = gn >> 6,  d = gn & 63;
        int bh = b * NH + h;
        int tile = s >> 6, kb = (s & 63) >> 2;
        bf16x4 t;
        for (int r = 0; r < 4; ++r) t[r] = (bf16)acc[i][j][r];
        *(bf16x4*)(C + ((((size_t)bh * 32 + tile) * 16 + kb) * 64 + d) * 4) = t;
      }
  }
}

// ---------------------------------------------------------------------------
// Flash attention: S^T = K*Q^T via 32x32x16 MFMA; P stays in registers.
// KV-split via blockIdx.z; partial O BF16 + fp32 row-sums.
// grid (bh=32, q=16, zh=2): XCD = bh%8 -> each bh's K/V served from one L2.
// ---------------------------------------------------------------------------
__global__ __launch_bounds__(256, 4) void attn_kernel(
    const bf16* __restrict__ Qh, const bf16* __restrict__ Kh, const bf16* __restrict__ Vperm,
    const float* __restrict__ mask, bf16* __restrict__ Opart, float* __restrict__ Lpart)
{
  __shared__ __align__(16) bf16 Ks[64 * 64];    // [kv][d], chunk XOR-swizzled
  __shared__ __align__(16) bf16 Vts[64 * 64];   // [kb][d][4] linear (permuted)
  __shared__ __align__(16) float masks2[64];

  const int bh = blockIdx.x;                    // bh on x: XCD-local K/V reuse
  const int b = bh >> 4;
  const int q0 = blockIdx.y * 128;
  const int zh = blockIdx.z;                    // kv half
  const int tid = threadIdx.x;
  const int lane = tid & 63;
  const int wave = tid >> 6;
  const int ln = lane & 31;
  const int hi = lane >> 5;
  const float SC2 = 0.125f * LOG2E;

  // hoisted Q B-frags: B[k=d][n=q] = Q[q][d], d = c*16 + hi*8 + u
  const int qg = q0 + wave * 32 + ln;
  bf16x8 qf[4];
  {
    const bf16* qrow = Qh + ((size_t)bh * S_LEN + qg) * DKV;
    for (int c = 0; c < 4; ++c)
      qf[c] = *(const bf16x8*)(qrow + c * 16 + hi * 8);
  }

  f32x16 O[2];
  for (int nb = 0; nb < 2; ++nb)
    for (int i = 0; i < 16; ++i) O[nb][i] = 0.f;
  float lsum = 0.f;

  for (int it = 0; it < 16; ++it) {
    const int kv0 = zh * 1024 + it * 64;
    __syncthreads();  // protect Ks/Vts/masks2 from previous iteration's readers
    const bf16* vtile = Vperm + ((size_t)bh * 32 + (kv0 >> 6)) * 4096;
    for (int j = 0; j < 2; ++j) {
      int base = j * 256 + wave * 64;       // wave-uniform
      int idx = base + lane;
      int r = idx >> 3;
      int cc = (idx & 7) ^ (r & 7);
      async_load16(Kh + ((size_t)bh * S_LEN + kv0 + r) * DKV + cc * 8,
                   (char*)Ks + (size_t)base * 16);
      async_load16(vtile + (size_t)idx * 8,
                   (char*)Vts + (size_t)base * 16);
    }
    if (tid < 64) masks2[tid] = mask[b * S_LEN + kv0 + tid] * LOG2E;
    __syncthreads();

    // S^T = K * Q^T  (A = K[kv][d], m=kv: 2 m-blocks; B = qf; 4 k-chunks)
    f32x16 Sm[2];
    for (int i = 0; i < 16; ++i) { Sm[0][i] = 0.f; Sm[1][i] = 0.f; }
    for (int c = 0; c < 4; ++c) {
      bf16x8 k0 = *(const bf16x8*)(Ks + ln * 64        + (((2 * c + hi) ^ (ln & 7)) << 3));
      bf16x8 k1 = *(const bf16x8*)(Ks + (32 + ln) * 64 + (((2 * c + hi) ^ (ln & 7)) << 3));
      Sm[0] = __builtin_amdgcn_mfma_f32_32x32x16_bf16(k0, qf[c], Sm[0], 0, 0, 0);
      Sm[1] = __builtin_amdgcn_mfma_f32_32x32x16_bf16(k1, qf[c], Sm[1], 0, 0, 0);
    }

    // P = exp2(S*SC2 + mask*LOG2E) in registers -> PV
    for (int cg = 0; cg < 4; ++cg) {
      int mb = cg >> 1, g = cg & 1;
      int koff = 32 * mb + 16 * g + 4 * hi;
      f32x4 mklo = *(const f32x4*)(masks2 + koff);
      f32x4 mkhi = *(const f32x4*)(masks2 + koff + 8);
      bf16x8 ap;
      float ls0 = 0.f;
      for (int u = 0; u < 4; ++u) {
        float p = __builtin_amdgcn_exp2f(Sm[mb][g * 8 + u] * SC2 + mklo[u]);
        ls0 += p; ap[u] = (bf16)p;
      }
      for (int u = 0; u < 4; ++u) {
        float p = __builtin_amdgcn_exp2f(Sm[mb][g * 8 + 4 + u] * SC2 + mkhi[u]);
        ls0 += p; ap[4 + u] = (bf16)p;
      }
      lsum += ls0;
      int kb0 = hi + 4 * g + 8 * mb;
      for (int nb = 0; nb < 2; ++nb) {
        int d = nb * 32 + ln;
        bf16x4 lo = *(const bf16x4*)(Vts + ((size_t)kb0 * 64 + d) * 4);
        bf16x4 hv = *(const bf16x4*)(Vts + ((size_t)(kb0 + 2) * 64 + d) * 4);
        bf16x8 bv;
        for (int u = 0; u < 4; ++u) { bv[u] = lo[u]; bv[u + 4] = hv[u]; }
        O[nb] = __builtin_amdgcn_mfma_f32_32x32x16_bf16(ap, bv, O[nb], 0, 0, 0);
      }
    }
  }

  // partial row sums
  float lt = lsum + __shfl_xor(lsum, 32, 64);
  if (lane < 32)
    Lpart[((size_t)zh * 32 + bh) * S_LEN + q0 + wave * 32 + ln] = lt;

  // partial O (un-normalized, bf16): Opart[zh][bh][q][d]
  bf16* ob = Opart + (((size_t)zh * 32 + bh) * S_LEN) * DKV;
  for (int g = 0; g < 4; ++g)
    for (int nb = 0; nb < 2; ++nb)
      for (int j = 0; j < 4; ++j) {
        int qrow = q0 + wave * 32 + j + 8 * g + 4 * hi;
        ob[(size_t)qrow * DKV + nb * 32 + ln] = (bf16)O[nb][g * 4 + j];
      }
}

// ---------------------------------------------------------------------------
// Out-GEMM: fused combine+normalize on A (bf16 partials); 32x128 tile, BK=64;
// Opart(k+1) register prefetch after barrier2 (same queue-safety as gemm_qkv).
// grid (m=128, n=8) = 1024 blocks -> 4 blocks/CU; XCD = m%8.
// ---------------------------------------------------------------------------
__global__ __launch_bounds__(256) void gemm_out(
    const bf16* __restrict__ Opart, const float* __restrict__ Lpart,
    const bf16* __restrict__ Wot, float* __restrict__ Cout)
{
  __shared__ __align__(16) bf16 As[32 * 64];     // 4KB  swizzled
  __shared__ __align__(16) bf16 Bs[128 * 64];    // 16KB swizzled
  __shared__ float rinv[NH * 32];                // 2KB

  const int m0 = blockIdx.x * 32;        // m on x: XCD-local Opart reuse
  const int n0 = blockIdx.y * 128;
  const int tid = threadIdx.x;
  const int lane = tid & 63;
  const int wave = tid >> 6;
  const int wm = (wave >> 1) * 16;
  const int wn = (wave & 1) * 64;
  const int row = lane & 15;
  const int quad = lane >> 4;
  const int b = m0 >> 11;
  const int s0 = m0 & 2047;

  // per-block row-sum reciprocals for all heads x 32 rows
  for (int u = 0; u < 2; ++u) {
    int idx = u * 256 + tid;
    int h = idx >> 5, r = idx & 31;
    float l = Lpart[((size_t)(b * NH + h)) * S_LEN + s0 + r]
            + Lpart[((size_t)(32 + b * NH + h)) * S_LEN + s0 + r];
    rinv[idx] = 1.0f / l;
  }

  f32x4 acc[4];
  for (int j = 0; j < 4; ++j) acc[j] = (f32x4){0.f, 0.f, 0.f, 0.f};

  const int arc = tid & 7;               // chunk col
  const int arr = tid >> 3;              // row 0..31
  const bf16* O0p = Opart + ((size_t)(b * NH) * S_LEN + s0 + arr) * DKV + arc * 8;
  const bf16* O1p = Opart + ((size_t)(32 + b * NH) * S_LEN + s0 + arr) * DKV + arc * 8;
  const size_t HSTEP = (size_t)S_LEN * DKV;    // per-head stride in Opart

  // preload Opart(0)
  bf16x8 h0 = *(const bf16x8*)(O0p);
  bf16x8 h1 = *(const bf16x8*)(O1p);

  for (int kt = 0; kt < 16; ++kt) {      // kt == head index (BK=64 == DKV)
    __syncthreads();                     // barrier1: prev iter's readers done
    for (int j = 0; j < 4; ++j) {        // Wot tile: async 1024 chunks, swizzled src
      int base = j * 256 + wave * 64;
      int idx = base + lane;
      int r = idx >> 3;
      int cc = (idx & 7) ^ (r & 7);
      async_load16(Wot + (size_t)(n0 + r) * DMODEL + kt * 64 + cc * 8,
                   (char*)Bs + (size_t)base * 16);
    }
    {
      float rv = rinv[kt * 32 + arr];
      bf16x8 o;
      for (int w = 0; w < 8; ++w)
        o[w] = (bf16)(((float)h0[w] + (float)h1[w]) * rv);
      *(bf16x8*)(As + arr * 64 + ((arc ^ (arr & 7)) << 3)) = o;
    }
    __syncthreads();                     // barrier2
    if (kt < 15) {                       // prefetch Opart(kt+1) during MFMA phase
      h0 = *(const bf16x8*)(O0p + (size_t)(kt + 1) * HSTEP);
      h1 = *(const bf16x8*)(O1p + (size_t)(kt + 1) * HSTEP);
    }
    for (int ks = 0; ks < 2; ++ks) {
      bf16x8 af, bfr[4];
      {
        int rr = wm + row;
        af = *(const bf16x8*)(As + rr * 64 + (((quad + ks * 4) ^ (rr & 7)) << 3));
      }
      for (int j = 0; j < 4; ++j) {
        int rr = wn + j * 16 + row;
        bfr[j] = *(const bf16x8*)(Bs + rr * 64 + (((quad + ks * 4) ^ (rr & 7)) << 3));
      }
      for (int j = 0; j < 4; ++j)
        acc[j] = __builtin_amdgcn_mfma_f32_16x16x32_bf16(af, bfr[j], acc[j], 0, 0, 0);
    }
  }

  for (int j = 0; j < 4; ++j)
    for (int r = 0; r < 4; ++r) {
      int gm = m0 + wm + quad * 4 + r;
      int gn = n0 + wn + j * 16 + row;
      Cout[(size_t)gm * DMODEL + gn] = acc[j][r];
    }
}

// ---------------------------------------------------------------------------
extern "C" void kernel_launch(void* const* d_in, const int* in_sizes, int n_in,
                              void* d_out, int out_size, void* d_ws, size_t ws_size,
                              hipStream_t stream)
{
  const float* query = (const float*)d_in[0];
  const float* key_  = (const float*)d_in[1];
  const float* value = (const float*)d_in[2];
  const float* mask  = (const float*)d_in[3];
  const float* Wq = (const float*)d_in[4];
  const float* Wk = (const float*)d_in[5];
  const float* Wv = (const float*)d_in[6];
  const float* Wo = (const float*)d_in[7];

  char* ws = (char*)d_ws;
  const size_t MB = (size_t)1 << 20;
  bf16* qh    = (bf16*)(ws + 0 * MB);    // 8MB [B,NH,S,DKV]
  bf16* kh    = (bf16*)(ws + 8 * MB);    // 8MB [B,NH,S,DKV]
  bf16* vperm = (bf16*)(ws + 16 * MB);   // 8MB PV-permuted V
  bf16* wot   = (bf16*)(ws + 24 * MB);   // 2MB (live until out-GEMM)
  bf16* Opart = (bf16*)(ws + 26 * MB);   // 16MB bf16 partials (26..42)
  bf16* wqt   = (bf16*)(ws + 26 * MB);   // 2MB each, dead after QKV GEMM
  bf16* wkt   = (bf16*)(ws + 28 * MB);   //   (overlaid by Opart afterwards)
  bf16* wvt   = (bf16*)(ws + 30 * MB);
  float* Lpart = (float*)(ws + 58 * MB); // 512KB row-sum partials

  transpose_w<<<dim3(32, 32, 4), dim3(32, 8), 0, stream>>>(Wq, Wk, Wv, Wo, wqt, wkt, wvt, wot);
  gemm_qkv<<<dim3(64, 8, 3), 256, 0, stream>>>(query, key_, value, wqt, wkt, wvt,
                                               qh, kh, vperm);
  attn_kernel<<<dim3(32, 16, 2), 256, 0, stream>>>(qh, kh, vperm, mask, Opart, Lpart);
  gemm_out<<<dim3(128, 8), 256, 0, stream>>>(Opart, Lpart, wot, (float*)d_out);
}